// Round 9
// baseline (1076.130 us; speedup 1.0000x reference)
//
#include <hip/hip_runtime.h>

// GCN forward, CSR-free: bucket staging IS the edge list.
//   binA2c: per-block LDS radix partition of 8192 edges into 512 dst-range
//     buckets (+ global deg count, 100k counters, low contention); one global
//     atomicAdd per (block,bucket) reserves staging space; coalesced flush.
//   gemm1: dinv[n]=rsqrt(deg+1) computed inline; xwd=(x@W1)*dinv.
//   aggB32: one block per bucket; LDS accumulators (stride 33, bank-spread);
//     streams staging, gathers xwd rows (32 in flight/wave), ds_add_f32;
//     writes agg1 = dinv * (self + sum) coalesced.
//   gemm2: h2wd=(relu(agg1+b1)@W2)*dinv.  aggB16: same, 16 feats (stride 17).
//   final: out = relu(agg2+b2)@Wf + bf.
// R7 lesson kept: no wave-serial shuffle epilogues inside gather kernels.

#define TPB 256
#define NBUCK 512
#define BCAP 7168    // mean 6250, sigma ~79 -> +11.6 sigma margin
#define CHUNK 8192   // edges per binA2 block
#define NPBMAX 256   // max nodes per bucket supported by LDS accumulators

// Phase A: block-local radix partition + global deg count + bulk staging append.
__global__ __launch_bounds__(512) void binA2c_kernel(
        const int* __restrict__ src, const int* __restrict__ dst,
        int* __restrict__ bcur, int* __restrict__ counts,
        unsigned* __restrict__ staging, int E, int NPB) {
    __shared__ unsigned packed[CHUNK];        // 32 KB
    __shared__ unsigned short buckb[CHUNK];   // 16 KB
    __shared__ int hist[NBUCK];
    __shared__ int scan_[NBUCK];
    __shared__ int lstart[NBUCK];
    __shared__ int lcur[NBUCK];
    __shared__ int gbase[NBUCK];
    int tid = threadIdx.x;
    int start = blockIdx.x * CHUNK;
    int sz = min(CHUNK, E - start);

    hist[tid] = 0;
    __syncthreads();
    for (int i = tid; i < sz; i += 512) {
        int d = dst[start + i];
        atomicAdd(&hist[(unsigned)d / (unsigned)NPB], 1);
        atomicAdd(&counts[d], 1);  // global deg count (low contention: 100k addrs)
    }
    __syncthreads();
    int v = hist[tid];
    scan_[tid] = v;
    __syncthreads();
    for (int dd = 1; dd < NBUCK; dd <<= 1) {
        int t = 0;
        if (tid >= dd) t = scan_[tid - dd];
        __syncthreads();
        scan_[tid] += t;
        __syncthreads();
    }
    lstart[tid] = scan_[tid] - v;
    lcur[tid] = 0;
    gbase[tid] = atomicAdd(&bcur[tid], v);  // one reservation per (block,bucket)
    __syncthreads();
    for (int i = tid; i < sz; i += 512) {
        unsigned d = (unsigned)dst[start + i];
        unsigned s = (unsigned)src[start + i];
        unsigned b = d / (unsigned)NPB;
        unsigned loc = d - b * (unsigned)NPB;
        int pos = atomicAdd(&lcur[b], 1);
        int si = lstart[b] + pos;
        packed[si] = (loc << 20) | s;
        buckb[si] = (unsigned short)b;
    }
    __syncthreads();
    for (int i = tid; i < sz; i += 512) {
        unsigned b = buckb[i];
        int dsti = gbase[b] + (i - lstart[b]);
        if (dsti < BCAP)
            staging[(size_t)b * BCAP + dsti] = packed[i];
    }
}

// xwd = (x @ W1) * dinv ; dinv computed here from counts (deg+1 self-loop).
// 2 nodes per thread.
__global__ void gemm1_kernel(const float* __restrict__ x, const float* __restrict__ W1,
                             const int* __restrict__ counts, float* __restrict__ dinv,
                             float* __restrict__ xwd, int N) {
    __shared__ float ws_[128 * 32];
    for (int i = threadIdx.x; i < 128 * 32; i += blockDim.x) ws_[i] = W1[i];
    __syncthreads();
    int n0 = blockIdx.x * 512 + threadIdx.x;
    int n1 = n0 + 256;
    if (n0 >= N) return;
    bool has1 = (n1 < N);
    float acc0[32], acc1[32];
#pragma unroll
    for (int j = 0; j < 32; ++j) { acc0[j] = 0.0f; acc1[j] = 0.0f; }
    const float4* xr0 = (const float4*)(x + (size_t)n0 * 128);
    const float4* xr1 = (const float4*)(x + (size_t)(has1 ? n1 : n0) * 128);
#pragma unroll 2
    for (int k4 = 0; k4 < 32; ++k4) {
        float4 xa = xr0[k4];
        float4 xb = xr1[k4];
        const float* wk = ws_ + k4 * 128;
#pragma unroll
        for (int j4 = 0; j4 < 8; ++j4) {
            float4 w0 = *(const float4*)(wk + j4 * 4);
            float4 w1 = *(const float4*)(wk + 32 + j4 * 4);
            float4 w2 = *(const float4*)(wk + 64 + j4 * 4);
            float4 w3 = *(const float4*)(wk + 96 + j4 * 4);
            acc0[j4 * 4 + 0] += xa.x * w0.x + xa.y * w1.x + xa.z * w2.x + xa.w * w3.x;
            acc0[j4 * 4 + 1] += xa.x * w0.y + xa.y * w1.y + xa.z * w2.y + xa.w * w3.y;
            acc0[j4 * 4 + 2] += xa.x * w0.z + xa.y * w1.z + xa.z * w2.z + xa.w * w3.z;
            acc0[j4 * 4 + 3] += xa.x * w0.w + xa.y * w1.w + xa.z * w2.w + xa.w * w3.w;
            acc1[j4 * 4 + 0] += xb.x * w0.x + xb.y * w1.x + xb.z * w2.x + xb.w * w3.x;
            acc1[j4 * 4 + 1] += xb.x * w0.y + xb.y * w1.y + xb.z * w2.y + xb.w * w3.y;
            acc1[j4 * 4 + 2] += xb.x * w0.z + xb.y * w1.z + xb.z * w2.z + xb.w * w3.z;
            acc1[j4 * 4 + 3] += xb.x * w0.w + xb.y * w1.w + xb.z * w2.w + xb.w * w3.w;
        }
    }
    float d0 = rsqrtf((float)(counts[n0] + 1));
    dinv[n0] = d0;
    float4* xp0 = (float4*)(xwd + (size_t)n0 * 32);
#pragma unroll
    for (int j4 = 0; j4 < 8; ++j4)
        xp0[j4] = make_float4(acc0[j4 * 4 + 0] * d0, acc0[j4 * 4 + 1] * d0,
                              acc0[j4 * 4 + 2] * d0, acc0[j4 * 4 + 3] * d0);
    if (has1) {
        float d1 = rsqrtf((float)(counts[n1] + 1));
        dinv[n1] = d1;
        float4* xp1 = (float4*)(xwd + (size_t)n1 * 32);
#pragma unroll
        for (int j4 = 0; j4 < 8; ++j4)
            xp1[j4] = make_float4(acc1[j4 * 4 + 0] * d1, acc1[j4 * 4 + 1] * d1,
                                  acc1[j4 * 4 + 2] * d1, acc1[j4 * 4 + 3] * d1);
    }
}

// One block per bucket, 32 feats. LDS accumulators stride 33 (bank-spread).
// q=tid&7 (float4 slot), es=tid>>3 (64 edge slots), x4 unroll -> 32/wave in flight.
__global__ __launch_bounds__(512) void aggB32_kernel(
        const int* __restrict__ bcur, const unsigned* __restrict__ staging,
        const float* __restrict__ dinv, const float* __restrict__ xwd,
        float* __restrict__ agg1, int N, int NPB) {
    __shared__ float aggL[NPBMAX * 33];  // 33.8 KB
    int b = blockIdx.x;
    int tid = threadIdx.x;
    int sz = min(bcur[b], BCAP);
    int n0 = b * NPB;
    int nn = min(NPB, N - n0);
    // init: self-loop term (xwd row; final *dinv gives dinv^2 * xw)
    for (int idx = tid; idx < nn * 32; idx += 512) {
        int r = idx >> 5, c = idx & 31;
        aggL[r * 33 + c] = xwd[(size_t)(n0 + r) * 32 + c];
    }
    __syncthreads();
    const unsigned* se = staging + (size_t)b * BCAP;
    int q = tid & 7;
    int es = tid >> 3;
    int i = es;
    for (; i + 192 < sz; i += 256) {
        unsigned e0 = se[i], e1 = se[i + 64], e2 = se[i + 128], e3 = se[i + 192];
        float4 v0 = *(const float4*)(xwd + (size_t)(e0 & 0xFFFFFu) * 32 + q * 4);
        float4 v1 = *(const float4*)(xwd + (size_t)(e1 & 0xFFFFFu) * 32 + q * 4);
        float4 v2 = *(const float4*)(xwd + (size_t)(e2 & 0xFFFFFu) * 32 + q * 4);
        float4 v3 = *(const float4*)(xwd + (size_t)(e3 & 0xFFFFFu) * 32 + q * 4);
        float* a0 = &aggL[(e0 >> 20) * 33 + q * 4];
        float* a1 = &aggL[(e1 >> 20) * 33 + q * 4];
        float* a2 = &aggL[(e2 >> 20) * 33 + q * 4];
        float* a3 = &aggL[(e3 >> 20) * 33 + q * 4];
        atomicAdd(a0 + 0, v0.x); atomicAdd(a0 + 1, v0.y);
        atomicAdd(a0 + 2, v0.z); atomicAdd(a0 + 3, v0.w);
        atomicAdd(a1 + 0, v1.x); atomicAdd(a1 + 1, v1.y);
        atomicAdd(a1 + 2, v1.z); atomicAdd(a1 + 3, v1.w);
        atomicAdd(a2 + 0, v2.x); atomicAdd(a2 + 1, v2.y);
        atomicAdd(a2 + 2, v2.z); atomicAdd(a2 + 3, v2.w);
        atomicAdd(a3 + 0, v3.x); atomicAdd(a3 + 1, v3.y);
        atomicAdd(a3 + 2, v3.z); atomicAdd(a3 + 3, v3.w);
    }
    for (; i < sz; i += 64) {
        unsigned e = se[i];
        float4 v = *(const float4*)(xwd + (size_t)(e & 0xFFFFFu) * 32 + q * 4);
        float* a = &aggL[(e >> 20) * 33 + q * 4];
        atomicAdd(a + 0, v.x); atomicAdd(a + 1, v.y);
        atomicAdd(a + 2, v.z); atomicAdd(a + 3, v.w);
    }
    __syncthreads();
    for (int idx = tid; idx < nn * 32; idx += 512) {
        int r = idx >> 5, c = idx & 31;
        agg1[(size_t)(n0 + r) * 32 + c] = aggL[r * 33 + c] * dinv[n0 + r];
    }
}

// h2wd = (relu(agg1 + b1) @ W2) * dinv[node]
__global__ void gemm2_kernel(const float* __restrict__ agg1, const float* __restrict__ W2,
                             const float* __restrict__ b1, const float* __restrict__ dinv,
                             float* __restrict__ h2wd, int N) {
    __shared__ float ws_[32 * 16];
    __shared__ float bs_[32];
    for (int i = threadIdx.x; i < 32 * 16; i += blockDim.x) ws_[i] = W2[i];
    if (threadIdx.x < 32) bs_[threadIdx.x] = b1[threadIdx.x];
    __syncthreads();
    int node = blockIdx.x * blockDim.x + threadIdx.x;
    if (node >= N) return;
    float h[32];
    const float4* ar = (const float4*)(agg1 + (size_t)node * 32);
#pragma unroll
    for (int k4 = 0; k4 < 8; ++k4) {
        float4 v = ar[k4];
        h[k4 * 4 + 0] = fmaxf(v.x + bs_[k4 * 4 + 0], 0.0f);
        h[k4 * 4 + 1] = fmaxf(v.y + bs_[k4 * 4 + 1], 0.0f);
        h[k4 * 4 + 2] = fmaxf(v.z + bs_[k4 * 4 + 2], 0.0f);
        h[k4 * 4 + 3] = fmaxf(v.w + bs_[k4 * 4 + 3], 0.0f);
    }
    float acc[16];
#pragma unroll
    for (int j = 0; j < 16; ++j) acc[j] = 0.0f;
#pragma unroll
    for (int k = 0; k < 32; ++k) {
        float hv = h[k];
#pragma unroll
        for (int j4 = 0; j4 < 4; ++j4) {
            float4 w = *(const float4*)(ws_ + k * 16 + j4 * 4);
            acc[j4 * 4 + 0] += hv * w.x;
            acc[j4 * 4 + 1] += hv * w.y;
            acc[j4 * 4 + 2] += hv * w.z;
            acc[j4 * 4 + 3] += hv * w.w;
        }
    }
    float d = dinv[node];
    float4* hp = (float4*)(h2wd + (size_t)node * 16);
#pragma unroll
    for (int j4 = 0; j4 < 4; ++j4)
        hp[j4] = make_float4(acc[j4 * 4 + 0] * d, acc[j4 * 4 + 1] * d,
                             acc[j4 * 4 + 2] * d, acc[j4 * 4 + 3] * d);
}

// One block per bucket, 16 feats. LDS accumulators stride 17.
// q=tid&3, es=tid>>2 (128 slots), x2 unroll -> 32/wave in flight.
__global__ __launch_bounds__(512) void aggB16_kernel(
        const int* __restrict__ bcur, const unsigned* __restrict__ staging,
        const float* __restrict__ dinv, const float* __restrict__ h2wd,
        float* __restrict__ agg2, int N, int NPB) {
    __shared__ float aggL[NPBMAX * 17];  // 17.4 KB
    int b = blockIdx.x;
    int tid = threadIdx.x;
    int sz = min(bcur[b], BCAP);
    int n0 = b * NPB;
    int nn = min(NPB, N - n0);
    for (int idx = tid; idx < nn * 16; idx += 512) {
        int r = idx >> 4, c = idx & 15;
        aggL[r * 17 + c] = h2wd[(size_t)(n0 + r) * 16 + c];
    }
    __syncthreads();
    const unsigned* se = staging + (size_t)b * BCAP;
    int q = tid & 3;
    int es = tid >> 2;
    int i = es;
    for (; i + 128 < sz; i += 256) {
        unsigned e0 = se[i], e1 = se[i + 128];
        float4 v0 = *(const float4*)(h2wd + (size_t)(e0 & 0xFFFFFu) * 16 + q * 4);
        float4 v1 = *(const float4*)(h2wd + (size_t)(e1 & 0xFFFFFu) * 16 + q * 4);
        float* a0 = &aggL[(e0 >> 20) * 17 + q * 4];
        float* a1 = &aggL[(e1 >> 20) * 17 + q * 4];
        atomicAdd(a0 + 0, v0.x); atomicAdd(a0 + 1, v0.y);
        atomicAdd(a0 + 2, v0.z); atomicAdd(a0 + 3, v0.w);
        atomicAdd(a1 + 0, v1.x); atomicAdd(a1 + 1, v1.y);
        atomicAdd(a1 + 2, v1.z); atomicAdd(a1 + 3, v1.w);
    }
    for (; i < sz; i += 128) {
        unsigned e = se[i];
        float4 v = *(const float4*)(h2wd + (size_t)(e & 0xFFFFFu) * 16 + q * 4);
        float* a = &aggL[(e >> 20) * 17 + q * 4];
        atomicAdd(a + 0, v.x); atomicAdd(a + 1, v.y);
        atomicAdd(a + 2, v.z); atomicAdd(a + 3, v.w);
    }
    __syncthreads();
    for (int idx = tid; idx < nn * 16; idx += 512) {
        int r = idx >> 4, c = idx & 15;
        agg2[(size_t)(n0 + r) * 16 + c] = aggL[r * 17 + c] * dinv[n0 + r];
    }
}

// out = relu(agg2 + b2) @ Wf + bf
__global__ void final_kernel(const float* __restrict__ agg2, const float* __restrict__ b2,
                             const float* __restrict__ Wf, const float* __restrict__ bf,
                             float* __restrict__ out, int N) {
    int i = blockIdx.x * blockDim.x + threadIdx.x;
    if (i >= N) return;
    const float4* ar = (const float4*)(agg2 + (size_t)i * 16);
    float acc = bf[0];
#pragma unroll
    for (int j4 = 0; j4 < 4; ++j4) {
        float4 v = ar[j4];
        acc += fmaxf(v.x + b2[j4 * 4 + 0], 0.0f) * Wf[j4 * 4 + 0];
        acc += fmaxf(v.y + b2[j4 * 4 + 1], 0.0f) * Wf[j4 * 4 + 1];
        acc += fmaxf(v.z + b2[j4 * 4 + 2], 0.0f) * Wf[j4 * 4 + 2];
        acc += fmaxf(v.w + b2[j4 * 4 + 3], 0.0f) * Wf[j4 * 4 + 3];
    }
    out[i] = acc;
}

extern "C" void kernel_launch(void* const* d_in, const int* in_sizes, int n_in,
                              void* d_out, int out_size, void* d_ws, size_t ws_size,
                              hipStream_t stream) {
    const float* x  = (const float*)d_in[0];
    const int*   ei = (const int*)d_in[1];
    const float* W1 = (const float*)d_in[2];
    const float* b1 = (const float*)d_in[3];
    const float* W2 = (const float*)d_in[4];
    const float* b2 = (const float*)d_in[5];
    const float* Wf = (const float*)d_in[6];
    const float* bf = (const float*)d_in[7];

    int N = in_sizes[0] / 128;
    int E = in_sizes[1] / 2;
    const int* src = ei;       // edge_index[0]
    const int* dst = ei + E;   // edge_index[1]
    int NPB = (N + NBUCK - 1) / NBUCK;  // 196 for N=100k; must be <= NPBMAX

    // Workspace layout: counts and bcur adjacent for one memset.
    size_t Np = ((size_t)N + 3) & ~(size_t)3;
    int* wsI      = (int*)d_ws;
    int* counts   = wsI;               // N
    int* bcur     = counts + Np;       // NBUCK
    float* dinv   = (float*)(bcur + NBUCK);   // N
    float* xwd    = dinv + Np;         // 32*N
    float* agg1   = xwd + 32 * Np;     // 32*N
    float* h2wd   = agg1 + 32 * Np;    // 16*N
    float* agg2   = h2wd + 16 * Np;    // 16*N
    unsigned* staging = (unsigned*)(agg2 + 16 * Np);  // NBUCK*BCAP (14.7 MB)
    float* out    = (float*)d_out;

    int nbG1 = (N + 511) / 512;
    int nbC  = (E + CHUNK - 1) / CHUNK;
    int nbN  = (N + TPB - 1) / TPB;

    hipMemsetAsync(counts, 0, (Np + NBUCK) * sizeof(int), stream);
    binA2c_kernel<<<nbC, 512, 0, stream>>>(src, dst, bcur, counts, staging, E, NPB);
    gemm1_kernel<<<nbG1, 256, 0, stream>>>(x, W1, counts, dinv, xwd, N);
    aggB32_kernel<<<NBUCK, 512, 0, stream>>>(bcur, staging, dinv, xwd, agg1, N, NPB);
    gemm2_kernel<<<nbN, TPB, 0, stream>>>(agg1, W2, b1, dinv, h2wd, N);
    aggB16_kernel<<<NBUCK, 512, 0, stream>>>(bcur, staging, dinv, h2wd, agg2, N, NPB);
    final_kernel<<<nbN, TPB, 0, stream>>>(agg2, b2, Wf, bf, out, N);
}

// Round 10
// 296.587 us; speedup vs baseline: 3.6284x; 3.6284x over previous
//
#include <hip/hip_runtime.h>

// GCN forward via two-level CSR build + gather aggregation (no atomics in the
// float path — R4/R9 showed both global and LDS atomic aggregation lose 5-10x
// to register-accumulate gather).
//   binA2: per-block LDS radix partition -> 256 dst-range buckets.
//   buildB: per-bucket LDS histogram+scan -> counts/offs/dinv + CSR.
//   gemm1: xwd = (x@W1)*dinv, stored BF16 (64B rows -> half gather traffic).
//   agg32h: agg1[d] = dinv[d]*(xwd[d]+sum xwd[s]); fp32 accum, 32 gathers in
//     flight/wave.  gemm2: h2wd = (relu(agg1+b1)@W2)*dinv, stored BF16 (32B).
//   agg16h: same gather for layer 2 -> agg2 fp32.  final: head.
// R7 lesson: no wave-serial shuffle epilogues inside gather kernels.

#define TPB 256
#define NBUCK 256
#define BCAP 16384   // bucket capacity; mean ~12512 -> large margin
#define CHUNK 8192   // edges per binA2 block

__device__ __forceinline__ unsigned f2bf(float f) {  // RNE fp32->bf16
    unsigned u = __float_as_uint(f);
    return (u + 0x7FFFu + ((u >> 16) & 1u)) >> 16;
}
__device__ __forceinline__ float bflo(unsigned u) { return __uint_as_float(u << 16); }
__device__ __forceinline__ float bfhi(unsigned u) { return __uint_as_float(u & 0xFFFF0000u); }

__global__ void zero_bcursor_kernel(int* __restrict__ bcur) {
    bcur[threadIdx.x] = 0;
}

// Phase A: block-local radix partition, then bulk append to global staging.
__global__ __launch_bounds__(256) void binA2_kernel(
        const int* __restrict__ src, const int* __restrict__ dst,
        int* __restrict__ bcur, unsigned* __restrict__ staging, int E, int NPB) {
    __shared__ unsigned packed[CHUNK];
    __shared__ unsigned char buckb[CHUNK];
    __shared__ int hist[NBUCK];
    __shared__ int scan_[NBUCK];
    __shared__ int lstart[NBUCK];
    __shared__ int lcur[NBUCK];
    __shared__ int gbase[NBUCK];
    int tid = threadIdx.x;
    int start = blockIdx.x * CHUNK;
    int sz = min(CHUNK, E - start);

    hist[tid] = 0;
    __syncthreads();
    for (int i = tid; i < sz; i += 256) {
        unsigned d = (unsigned)dst[start + i];
        atomicAdd(&hist[d / (unsigned)NPB], 1);
    }
    __syncthreads();
    int v = hist[tid];
    scan_[tid] = v;
    __syncthreads();
    for (int dd = 1; dd < NBUCK; dd <<= 1) {
        int t = 0;
        if (tid >= dd) t = scan_[tid - dd];
        __syncthreads();
        scan_[tid] += t;
        __syncthreads();
    }
    lstart[tid] = scan_[tid] - v;
    lcur[tid] = 0;
    gbase[tid] = atomicAdd(&bcur[tid], v);  // reserve once per (block,bucket)
    __syncthreads();
    for (int i = tid; i < sz; i += 256) {
        unsigned d = (unsigned)dst[start + i];
        unsigned s = (unsigned)src[start + i];
        unsigned b = d / (unsigned)NPB;
        unsigned loc = d - b * (unsigned)NPB;
        int pos = atomicAdd(&lcur[b], 1);
        int si = lstart[b] + pos;
        packed[si] = (loc << 20) | s;
        buckb[si] = (unsigned char)b;
    }
    __syncthreads();
    for (int i = tid; i < sz; i += 256) {
        unsigned b = buckb[i];
        int dsti = gbase[b] + (i - lstart[b]);
        if (dsti < BCAP)
            staging[(size_t)b * BCAP + dsti] = packed[i];
    }
}

// Exclusive scan of clamped bucket sizes -> bbase (single block of 256)
__global__ void bucket_scan_kernel(const int* __restrict__ bcur, int* __restrict__ bbase) {
    __shared__ int s[NBUCK];
    int tid = threadIdx.x;
    int v = min(bcur[tid], BCAP);
    s[tid] = v;
    __syncthreads();
    for (int d = 1; d < NBUCK; d <<= 1) {
        int t = 0;
        if (tid >= d) t = s[tid - d];
        __syncthreads();
        s[tid] += t;
        __syncthreads();
    }
    bbase[tid] = s[tid] - v;  // exclusive
}

// Phase B: one block (512 thr) per bucket. Histogram + scan + CSR placement.
__global__ void buildB_kernel(const int* __restrict__ bcur, const int* __restrict__ bbase,
                              const unsigned* __restrict__ staging,
                              int* __restrict__ offs, int* __restrict__ counts,
                              float* __restrict__ dinv, int* __restrict__ csr_src,
                              int N, int NPB) {
    __shared__ int hist[512];
    __shared__ int scan_[512];
    __shared__ int cur[512];
    int b = blockIdx.x;
    int tid = threadIdx.x;
    int sz = min(bcur[b], BCAP);
    int base = bbase[b];
    int n0 = b * NPB;
    int nn = min(NPB, N - n0);
    const unsigned* se = staging + (size_t)b * BCAP;

    hist[tid] = 0;
    __syncthreads();
    for (int i = tid; i < sz; i += 512)
        atomicAdd(&hist[se[i] >> 20], 1);
    __syncthreads();
    int h = hist[tid];
    scan_[tid] = h;
    __syncthreads();
    for (int d = 1; d < 512; d <<= 1) {
        int t = 0;
        if (tid >= d) t = scan_[tid - d];
        __syncthreads();
        scan_[tid] += t;
        __syncthreads();
    }
    int excl = scan_[tid] - h;
    cur[tid] = excl;
    if (tid < nn) {
        int node = n0 + tid;
        offs[node] = base + excl;
        counts[node] = h;
        dinv[node] = rsqrtf((float)(h + 1));  // +1 self-loop
    }
    __syncthreads();
    for (int i = tid; i < sz; i += 512) {
        unsigned p = se[i];
        int pos = atomicAdd(&cur[p >> 20], 1);
        csr_src[base + pos] = (int)(p & 0xFFFFFu);
    }
}

// xwd(bf16) = (x @ W1) * dinv[node] ; 2 nodes per thread.
__global__ void gemm1_kernel(const float* __restrict__ x, const float* __restrict__ W1,
                             const float* __restrict__ dinv, unsigned* __restrict__ xwd, int N) {
    __shared__ float ws_[128 * 32];
    for (int i = threadIdx.x; i < 128 * 32; i += blockDim.x) ws_[i] = W1[i];
    __syncthreads();
    int n0 = blockIdx.x * 512 + threadIdx.x;
    int n1 = n0 + 256;
    if (n0 >= N) return;
    bool has1 = (n1 < N);
    float acc0[32], acc1[32];
#pragma unroll
    for (int j = 0; j < 32; ++j) { acc0[j] = 0.0f; acc1[j] = 0.0f; }
    const float4* xr0 = (const float4*)(x + (size_t)n0 * 128);
    const float4* xr1 = (const float4*)(x + (size_t)(has1 ? n1 : n0) * 128);
#pragma unroll 2
    for (int k4 = 0; k4 < 32; ++k4) {
        float4 xa = xr0[k4];
        float4 xb = xr1[k4];
        const float* wk = ws_ + k4 * 128;
#pragma unroll
        for (int j4 = 0; j4 < 8; ++j4) {
            float4 w0 = *(const float4*)(wk + j4 * 4);
            float4 w1 = *(const float4*)(wk + 32 + j4 * 4);
            float4 w2 = *(const float4*)(wk + 64 + j4 * 4);
            float4 w3 = *(const float4*)(wk + 96 + j4 * 4);
            acc0[j4 * 4 + 0] += xa.x * w0.x + xa.y * w1.x + xa.z * w2.x + xa.w * w3.x;
            acc0[j4 * 4 + 1] += xa.x * w0.y + xa.y * w1.y + xa.z * w2.y + xa.w * w3.y;
            acc0[j4 * 4 + 2] += xa.x * w0.z + xa.y * w1.z + xa.z * w2.z + xa.w * w3.z;
            acc0[j4 * 4 + 3] += xa.x * w0.w + xa.y * w1.w + xa.z * w2.w + xa.w * w3.w;
            acc1[j4 * 4 + 0] += xb.x * w0.x + xb.y * w1.x + xb.z * w2.x + xb.w * w3.x;
            acc1[j4 * 4 + 1] += xb.x * w0.y + xb.y * w1.y + xb.z * w2.y + xb.w * w3.y;
            acc1[j4 * 4 + 2] += xb.x * w0.z + xb.y * w1.z + xb.z * w2.z + xb.w * w3.z;
            acc1[j4 * 4 + 3] += xb.x * w0.w + xb.y * w1.w + xb.z * w2.w + xb.w * w3.w;
        }
    }
    float d0 = dinv[n0];
    unsigned pk[16];
#pragma unroll
    for (int j = 0; j < 16; ++j)
        pk[j] = f2bf(acc0[2 * j] * d0) | (f2bf(acc0[2 * j + 1] * d0) << 16);
    uint4* xp0 = (uint4*)(xwd + (size_t)n0 * 16);
    xp0[0] = make_uint4(pk[0], pk[1], pk[2], pk[3]);
    xp0[1] = make_uint4(pk[4], pk[5], pk[6], pk[7]);
    xp0[2] = make_uint4(pk[8], pk[9], pk[10], pk[11]);
    xp0[3] = make_uint4(pk[12], pk[13], pk[14], pk[15]);
    if (has1) {
        float d1 = dinv[n1];
#pragma unroll
        for (int j = 0; j < 16; ++j)
            pk[j] = f2bf(acc1[2 * j] * d1) | (f2bf(acc1[2 * j + 1] * d1) << 16);
        uint4* xp1 = (uint4*)(xwd + (size_t)n1 * 16);
        xp1[0] = make_uint4(pk[0], pk[1], pk[2], pk[3]);
        xp1[1] = make_uint4(pk[4], pk[5], pk[6], pk[7]);
        xp1[2] = make_uint4(pk[8], pk[9], pk[10], pk[11]);
        xp1[3] = make_uint4(pk[12], pk[13], pk[14], pk[15]);
    }
}

// One wave per node, bf16 rows (64B): q=lane&3 picks uint4 (8 bf16),
// g=lane>>2 (16 groups) x2 unroll -> 32 row-gathers in flight. fp32 accum.
__global__ void agg32h_kernel(const int* __restrict__ offs, const int* __restrict__ counts,
                              const int* __restrict__ csr_src, const float* __restrict__ dinv,
                              const unsigned* __restrict__ xwd, float* __restrict__ agg, int N) {
    int wave = threadIdx.x >> 6;
    int lane = threadIdx.x & 63;
    int node = blockIdx.x * 4 + wave;
    if (node >= N) return;
    int q = lane & 3;
    int g = lane >> 2;
    int off = offs[node];
    int deg = counts[node];
    float acc[8];
#pragma unroll
    for (int k = 0; k < 8; ++k) acc[k] = 0.f;
    if (g == 0) {
        uint4 v = ((const uint4*)(xwd + (size_t)node * 16))[q];
        acc[0] = bflo(v.x); acc[1] = bfhi(v.x);
        acc[2] = bflo(v.y); acc[3] = bfhi(v.y);
        acc[4] = bflo(v.z); acc[5] = bfhi(v.z);
        acc[6] = bflo(v.w); acc[7] = bfhi(v.w);
    }
    int i = g;
    for (; i + 16 < deg; i += 32) {  // 2 independent gathers per group
        int s0 = csr_src[off + i];
        int s1 = csr_src[off + i + 16];
        uint4 v0 = ((const uint4*)(xwd + (size_t)s0 * 16))[q];
        uint4 v1 = ((const uint4*)(xwd + (size_t)s1 * 16))[q];
        acc[0] += bflo(v0.x) + bflo(v1.x); acc[1] += bfhi(v0.x) + bfhi(v1.x);
        acc[2] += bflo(v0.y) + bflo(v1.y); acc[3] += bfhi(v0.y) + bfhi(v1.y);
        acc[4] += bflo(v0.z) + bflo(v1.z); acc[5] += bfhi(v0.z) + bfhi(v1.z);
        acc[6] += bflo(v0.w) + bflo(v1.w); acc[7] += bfhi(v0.w) + bfhi(v1.w);
    }
    for (; i < deg; i += 16) {
        int s = csr_src[off + i];
        uint4 v = ((const uint4*)(xwd + (size_t)s * 16))[q];
        acc[0] += bflo(v.x); acc[1] += bfhi(v.x);
        acc[2] += bflo(v.y); acc[3] += bfhi(v.y);
        acc[4] += bflo(v.z); acc[5] += bfhi(v.z);
        acc[6] += bflo(v.w); acc[7] += bfhi(v.w);
    }
#pragma unroll
    for (int d = 32; d >= 4; d >>= 1) {
#pragma unroll
        for (int k = 0; k < 8; ++k) acc[k] += __shfl_down(acc[k], d, 64);
    }
    if (g == 0) {
        float dv = dinv[node];
        float* op = agg + (size_t)node * 32 + q * 8;
        ((float4*)op)[0] = make_float4(acc[0] * dv, acc[1] * dv, acc[2] * dv, acc[3] * dv);
        ((float4*)op)[1] = make_float4(acc[4] * dv, acc[5] * dv, acc[6] * dv, acc[7] * dv);
    }
}

// h2wd(bf16) = (relu(agg1 + b1) @ W2) * dinv[node]
__global__ void gemm2_kernel(const float* __restrict__ agg1, const float* __restrict__ W2,
                             const float* __restrict__ b1, const float* __restrict__ dinv,
                             unsigned* __restrict__ h2wd, int N) {
    __shared__ float ws_[32 * 16];
    __shared__ float bs_[32];
    for (int i = threadIdx.x; i < 32 * 16; i += blockDim.x) ws_[i] = W2[i];
    if (threadIdx.x < 32) bs_[threadIdx.x] = b1[threadIdx.x];
    __syncthreads();
    int node = blockIdx.x * blockDim.x + threadIdx.x;
    if (node >= N) return;
    float h[32];
    const float4* ar = (const float4*)(agg1 + (size_t)node * 32);
#pragma unroll
    for (int k4 = 0; k4 < 8; ++k4) {
        float4 v = ar[k4];
        h[k4 * 4 + 0] = fmaxf(v.x + bs_[k4 * 4 + 0], 0.0f);
        h[k4 * 4 + 1] = fmaxf(v.y + bs_[k4 * 4 + 1], 0.0f);
        h[k4 * 4 + 2] = fmaxf(v.z + bs_[k4 * 4 + 2], 0.0f);
        h[k4 * 4 + 3] = fmaxf(v.w + bs_[k4 * 4 + 3], 0.0f);
    }
    float acc[16];
#pragma unroll
    for (int j = 0; j < 16; ++j) acc[j] = 0.0f;
#pragma unroll
    for (int k = 0; k < 32; ++k) {
        float hv = h[k];
#pragma unroll
        for (int j4 = 0; j4 < 4; ++j4) {
            float4 w = *(const float4*)(ws_ + k * 16 + j4 * 4);
            acc[j4 * 4 + 0] += hv * w.x;
            acc[j4 * 4 + 1] += hv * w.y;
            acc[j4 * 4 + 2] += hv * w.z;
            acc[j4 * 4 + 3] += hv * w.w;
        }
    }
    float d = dinv[node];
    unsigned pk[8];
#pragma unroll
    for (int j = 0; j < 8; ++j)
        pk[j] = f2bf(acc[2 * j] * d) | (f2bf(acc[2 * j + 1] * d) << 16);
    uint4* hp = (uint4*)(h2wd + (size_t)node * 8);
    hp[0] = make_uint4(pk[0], pk[1], pk[2], pk[3]);
    hp[1] = make_uint4(pk[4], pk[5], pk[6], pk[7]);
}

// One wave per node, bf16 rows (32B): q=lane&1, g=lane>>1 (32 groups)
// -> 32 gathers in flight. fp32 accum, agg2 written fp32.
__global__ void agg16h_kernel(const int* __restrict__ offs, const int* __restrict__ counts,
                              const int* __restrict__ csr_src, const float* __restrict__ dinv,
                              const unsigned* __restrict__ h2wd, float* __restrict__ agg, int N) {
    int wave = threadIdx.x >> 6;
    int lane = threadIdx.x & 63;
    int node = blockIdx.x * 4 + wave;
    if (node >= N) return;
    int q = lane & 1;
    int g = lane >> 1;
    int off = offs[node];
    int deg = counts[node];
    float acc[8];
#pragma unroll
    for (int k = 0; k < 8; ++k) acc[k] = 0.f;
    if (g == 0) {
        uint4 v = ((const uint4*)(h2wd + (size_t)node * 8))[q];
        acc[0] = bflo(v.x); acc[1] = bfhi(v.x);
        acc[2] = bflo(v.y); acc[3] = bfhi(v.y);
        acc[4] = bflo(v.z); acc[5] = bfhi(v.z);
        acc[6] = bflo(v.w); acc[7] = bfhi(v.w);
    }
    for (int i = g; i < deg; i += 32) {
        int s = csr_src[off + i];
        uint4 v = ((const uint4*)(h2wd + (size_t)s * 8))[q];
        acc[0] += bflo(v.x); acc[1] += bfhi(v.x);
        acc[2] += bflo(v.y); acc[3] += bfhi(v.y);
        acc[4] += bflo(v.z); acc[5] += bfhi(v.z);
        acc[6] += bflo(v.w); acc[7] += bfhi(v.w);
    }
#pragma unroll
    for (int d = 32; d >= 2; d >>= 1) {
#pragma unroll
        for (int k = 0; k < 8; ++k) acc[k] += __shfl_down(acc[k], d, 64);
    }
    if (g == 0) {
        float dv = dinv[node];
        float* op = agg + (size_t)node * 16 + q * 8;
        ((float4*)op)[0] = make_float4(acc[0] * dv, acc[1] * dv, acc[2] * dv, acc[3] * dv);
        ((float4*)op)[1] = make_float4(acc[4] * dv, acc[5] * dv, acc[6] * dv, acc[7] * dv);
    }
}

// out = relu(agg2 + b2) @ Wf + bf
__global__ void final_kernel(const float* __restrict__ agg2, const float* __restrict__ b2,
                             const float* __restrict__ Wf, const float* __restrict__ bf,
                             float* __restrict__ out, int N) {
    int i = blockIdx.x * blockDim.x + threadIdx.x;
    if (i >= N) return;
    const float4* ar = (const float4*)(agg2 + (size_t)i * 16);
    float acc = bf[0];
#pragma unroll
    for (int j4 = 0; j4 < 4; ++j4) {
        float4 v = ar[j4];
        acc += fmaxf(v.x + b2[j4 * 4 + 0], 0.0f) * Wf[j4 * 4 + 0];
        acc += fmaxf(v.y + b2[j4 * 4 + 1], 0.0f) * Wf[j4 * 4 + 1];
        acc += fmaxf(v.z + b2[j4 * 4 + 2], 0.0f) * Wf[j4 * 4 + 2];
        acc += fmaxf(v.w + b2[j4 * 4 + 3], 0.0f) * Wf[j4 * 4 + 3];
    }
    out[i] = acc;
}

extern "C" void kernel_launch(void* const* d_in, const int* in_sizes, int n_in,
                              void* d_out, int out_size, void* d_ws, size_t ws_size,
                              hipStream_t stream) {
    const float* x  = (const float*)d_in[0];
    const int*   ei = (const int*)d_in[1];
    const float* W1 = (const float*)d_in[2];
    const float* b1 = (const float*)d_in[3];
    const float* W2 = (const float*)d_in[4];
    const float* b2 = (const float*)d_in[5];
    const float* Wf = (const float*)d_in[6];
    const float* bf = (const float*)d_in[7];

    int N = in_sizes[0] / 128;
    int E = in_sizes[1] / 2;
    const int* src = ei;       // edge_index[0]
    const int* dst = ei + E;   // edge_index[1]
    int NPB = (N + NBUCK - 1) / NBUCK;  // 391 for N=100k

    // Workspace layout
    size_t Np = ((size_t)N + 3) & ~(size_t)3;
    size_t Ep = ((size_t)E + 3) & ~(size_t)3;
    int* wsI      = (int*)d_ws;
    int* counts   = wsI;                 // N
    int* offs     = counts + Np;         // N
    int* bcur     = offs + Np;           // 256
    int* bbase    = bcur + NBUCK;        // 256
    int* csr_src  = bbase + NBUCK;       // E
    float* dinv   = (float*)(csr_src + Ep);     // N
    unsigned* xwd = (unsigned*)(dinv + Np);     // 16*N u32 (bf16 rows, 64B)
    float* agg1   = (float*)(xwd + 16 * Np);    // 32*N f32
    unsigned* h2wd= (unsigned*)(agg1 + 32 * Np);// 8*N u32 (bf16 rows, 32B)
    float* agg2   = (float*)(h2wd + 8 * Np);    // 16*N f32
    float* out    = (float*)d_out;
    // Staging (16.8 MB) aliases agg1+h2wd+agg2 (22.4 MB): written by binA2,
    // read last by buildB; agg1 first written by agg32h (later). No overlap.
    unsigned* staging = (unsigned*)agg1;

    int nbG1 = (N + 511) / 512;
    int nbC = (E + CHUNK - 1) / CHUNK;
    int nbN = (N + TPB - 1) / TPB;
    int nbW = (N + 3) / 4;  // one wave (of 4/block) per node

    zero_bcursor_kernel<<<1, NBUCK, 0, stream>>>(bcur);
    binA2_kernel<<<nbC, 256, 0, stream>>>(src, dst, bcur, staging, E, NPB);
    bucket_scan_kernel<<<1, NBUCK, 0, stream>>>(bcur, bbase);
    buildB_kernel<<<NBUCK, 512, 0, stream>>>(bcur, bbase, staging, offs, counts,
                                             dinv, csr_src, N, NPB);
    gemm1_kernel<<<nbG1, 256, 0, stream>>>(x, W1, dinv, xwd, N);
    agg32h_kernel<<<nbW, TPB, 0, stream>>>(offs, counts, csr_src, dinv, xwd, agg1, N);
    gemm2_kernel<<<nbN, TPB, 0, stream>>>(agg1, W2, b1, dinv, h2wd, N);
    agg16h_kernel<<<nbW, TPB, 0, stream>>>(offs, counts, csr_src, dinv, h2wd, agg2, N);
    final_kernel<<<nbN, TPB, 0, stream>>>(agg2, b2, Wf, bf, out, N);
}

// Round 11
// 286.537 us; speedup vs baseline: 3.7556x; 1.0351x over previous
//
#include <hip/hip_runtime.h>

// GCN forward via two-level CSR build + gather aggregation (no atomics in the
// float path — R4/R9: atomic aggregation loses 5-10x to register gather).
//   binA2: per-block LDS radix partition -> 256 dst-range buckets.
//   buildB: per-bucket LDS histogram+scan -> counts/offs/dinv + CSR.
//   gemm1: xwd = (x@W1)*dinv, BF16 rows (64B). 4 thr/node x 8 cols ->
//     grid 1563 blocks (R10: 2-node/thr gave 196 blocks, 7.8% occupancy).
//   agg32h: agg1 = dinv*(self+sum), fp32 accum, ~32 gathers in flight/wave.
//   gemm2: h2wd = (relu(agg1+b1)@W2)*dinv, BF16 (32B). agg16h: layer-2 gather.
//   final: out = relu(agg2+b2)@Wf + bf.
// R7 lesson: no wave-serial shuffle epilogues inside gather kernels.

#define TPB 256
#define NBUCK 256
#define BCAP 16384   // bucket capacity; mean ~12512 -> large margin
#define CHUNK 8192   // edges per binA2 block

__device__ __forceinline__ unsigned f2bf(float f) {  // RNE fp32->bf16
    unsigned u = __float_as_uint(f);
    return (u + 0x7FFFu + ((u >> 16) & 1u)) >> 16;
}
__device__ __forceinline__ float bflo(unsigned u) { return __uint_as_float(u << 16); }
__device__ __forceinline__ float bfhi(unsigned u) { return __uint_as_float(u & 0xFFFF0000u); }

__global__ void zero_bcursor_kernel(int* __restrict__ bcur) {
    bcur[threadIdx.x] = 0;
}

// Phase A: block-local radix partition, then bulk append to global staging.
__global__ __launch_bounds__(256) void binA2_kernel(
        const int* __restrict__ src, const int* __restrict__ dst,
        int* __restrict__ bcur, unsigned* __restrict__ staging, int E, int NPB) {
    __shared__ unsigned packed[CHUNK];
    __shared__ unsigned char buckb[CHUNK];
    __shared__ int hist[NBUCK];
    __shared__ int scan_[NBUCK];
    __shared__ int lstart[NBUCK];
    __shared__ int lcur[NBUCK];
    __shared__ int gbase[NBUCK];
    int tid = threadIdx.x;
    int start = blockIdx.x * CHUNK;
    int sz = min(CHUNK, E - start);

    hist[tid] = 0;
    __syncthreads();
    for (int i = tid; i < sz; i += 256) {
        unsigned d = (unsigned)dst[start + i];
        atomicAdd(&hist[d / (unsigned)NPB], 1);
    }
    __syncthreads();
    int v = hist[tid];
    scan_[tid] = v;
    __syncthreads();
    for (int dd = 1; dd < NBUCK; dd <<= 1) {
        int t = 0;
        if (tid >= dd) t = scan_[tid - dd];
        __syncthreads();
        scan_[tid] += t;
        __syncthreads();
    }
    lstart[tid] = scan_[tid] - v;
    lcur[tid] = 0;
    gbase[tid] = atomicAdd(&bcur[tid], v);  // reserve once per (block,bucket)
    __syncthreads();
    for (int i = tid; i < sz; i += 256) {
        unsigned d = (unsigned)dst[start + i];
        unsigned s = (unsigned)src[start + i];
        unsigned b = d / (unsigned)NPB;
        unsigned loc = d - b * (unsigned)NPB;
        int pos = atomicAdd(&lcur[b], 1);
        int si = lstart[b] + pos;
        packed[si] = (loc << 20) | s;
        buckb[si] = (unsigned char)b;
    }
    __syncthreads();
    for (int i = tid; i < sz; i += 256) {
        unsigned b = buckb[i];
        int dsti = gbase[b] + (i - lstart[b]);
        if (dsti < BCAP)
            staging[(size_t)b * BCAP + dsti] = packed[i];
    }
}

// Exclusive scan of clamped bucket sizes -> bbase (single block of 256)
__global__ void bucket_scan_kernel(const int* __restrict__ bcur, int* __restrict__ bbase) {
    __shared__ int s[NBUCK];
    int tid = threadIdx.x;
    int v = min(bcur[tid], BCAP);
    s[tid] = v;
    __syncthreads();
    for (int d = 1; d < NBUCK; d <<= 1) {
        int t = 0;
        if (tid >= d) t = s[tid - d];
        __syncthreads();
        s[tid] += t;
        __syncthreads();
    }
    bbase[tid] = s[tid] - v;  // exclusive
}

// Phase B: one block (512 thr) per bucket. Histogram + scan + CSR placement.
__global__ void buildB_kernel(const int* __restrict__ bcur, const int* __restrict__ bbase,
                              const unsigned* __restrict__ staging,
                              int* __restrict__ offs, int* __restrict__ counts,
                              float* __restrict__ dinv, int* __restrict__ csr_src,
                              int N, int NPB) {
    __shared__ int hist[512];
    __shared__ int scan_[512];
    __shared__ int cur[512];
    int b = blockIdx.x;
    int tid = threadIdx.x;
    int sz = min(bcur[b], BCAP);
    int base = bbase[b];
    int n0 = b * NPB;
    int nn = min(NPB, N - n0);
    const unsigned* se = staging + (size_t)b * BCAP;

    hist[tid] = 0;
    __syncthreads();
    for (int i = tid; i < sz; i += 512)
        atomicAdd(&hist[se[i] >> 20], 1);
    __syncthreads();
    int h = hist[tid];
    scan_[tid] = h;
    __syncthreads();
    for (int d = 1; d < 512; d <<= 1) {
        int t = 0;
        if (tid >= d) t = scan_[tid - d];
        __syncthreads();
        scan_[tid] += t;
        __syncthreads();
    }
    int excl = scan_[tid] - h;
    cur[tid] = excl;
    if (tid < nn) {
        int node = n0 + tid;
        offs[node] = base + excl;
        counts[node] = h;
        dinv[node] = rsqrtf((float)(h + 1));  // +1 self-loop
    }
    __syncthreads();
    for (int i = tid; i < sz; i += 512) {
        unsigned p = se[i];
        int pos = atomicAdd(&cur[p >> 20], 1);
        csr_src[base + pos] = (int)(p & 0xFFFFFu);
    }
}

// xwd(bf16) = (x @ W1) * dinv[node].  4 threads/node x 8 cols; grid (N+63)/64.
__global__ __launch_bounds__(256) void gemm1_kernel(
        const float* __restrict__ x, const float* __restrict__ W1,
        const float* __restrict__ dinv, unsigned* __restrict__ xwd, int N) {
    __shared__ float ws_[128 * 32];
    for (int i = threadIdx.x; i < 128 * 32; i += blockDim.x) ws_[i] = W1[i];
    __syncthreads();
    int t = threadIdx.x;
    int node = blockIdx.x * 64 + (t >> 2);
    if (node >= N) return;
    int jq = (t & 3) * 8;  // 8 output cols
    float acc[8];
#pragma unroll
    for (int j = 0; j < 8; ++j) acc[j] = 0.0f;
    const float4* xr = (const float4*)(x + (size_t)node * 128);
#pragma unroll 4
    for (int k4 = 0; k4 < 32; ++k4) {
        float4 xv = xr[k4];
        const float* wb = ws_ + (k4 * 4) * 32 + jq;
        float4 a0 = *(const float4*)(wb);
        float4 a1 = *(const float4*)(wb + 4);
        float4 b0 = *(const float4*)(wb + 32);
        float4 b1v = *(const float4*)(wb + 36);
        float4 c0 = *(const float4*)(wb + 64);
        float4 c1 = *(const float4*)(wb + 68);
        float4 d0 = *(const float4*)(wb + 96);
        float4 d1 = *(const float4*)(wb + 100);
        acc[0] += xv.x * a0.x + xv.y * b0.x + xv.z * c0.x + xv.w * d0.x;
        acc[1] += xv.x * a0.y + xv.y * b0.y + xv.z * c0.y + xv.w * d0.y;
        acc[2] += xv.x * a0.z + xv.y * b0.z + xv.z * c0.z + xv.w * d0.z;
        acc[3] += xv.x * a0.w + xv.y * b0.w + xv.z * c0.w + xv.w * d0.w;
        acc[4] += xv.x * a1.x + xv.y * b1v.x + xv.z * c1.x + xv.w * d1.x;
        acc[5] += xv.x * a1.y + xv.y * b1v.y + xv.z * c1.y + xv.w * d1.y;
        acc[6] += xv.x * a1.z + xv.y * b1v.z + xv.z * c1.z + xv.w * d1.z;
        acc[7] += xv.x * a1.w + xv.y * b1v.w + xv.z * c1.w + xv.w * d1.w;
    }
    float d = dinv[node];
    unsigned pk0 = f2bf(acc[0] * d) | (f2bf(acc[1] * d) << 16);
    unsigned pk1 = f2bf(acc[2] * d) | (f2bf(acc[3] * d) << 16);
    unsigned pk2 = f2bf(acc[4] * d) | (f2bf(acc[5] * d) << 16);
    unsigned pk3 = f2bf(acc[6] * d) | (f2bf(acc[7] * d) << 16);
    ((uint4*)(xwd + (size_t)node * 16))[t & 3] = make_uint4(pk0, pk1, pk2, pk3);
}

// One wave per node, bf16 rows (64B): q=lane&3 picks uint4 (8 bf16),
// g=lane>>2 (16 groups) x2 unroll -> 32 row-gathers in flight. fp32 accum.
__global__ void agg32h_kernel(const int* __restrict__ offs, const int* __restrict__ counts,
                              const int* __restrict__ csr_src, const float* __restrict__ dinv,
                              const unsigned* __restrict__ xwd, float* __restrict__ agg, int N) {
    int wave = threadIdx.x >> 6;
    int lane = threadIdx.x & 63;
    int node = blockIdx.x * 4 + wave;
    if (node >= N) return;
    int q = lane & 3;
    int g = lane >> 2;
    int off = offs[node];
    int deg = counts[node];
    float acc[8];
#pragma unroll
    for (int k = 0; k < 8; ++k) acc[k] = 0.f;
    if (g == 0) {
        uint4 v = ((const uint4*)(xwd + (size_t)node * 16))[q];
        acc[0] = bflo(v.x); acc[1] = bfhi(v.x);
        acc[2] = bflo(v.y); acc[3] = bfhi(v.y);
        acc[4] = bflo(v.z); acc[5] = bfhi(v.z);
        acc[6] = bflo(v.w); acc[7] = bfhi(v.w);
    }
    int i = g;
    for (; i + 16 < deg; i += 32) {  // 2 independent gathers per group
        int s0 = csr_src[off + i];
        int s1 = csr_src[off + i + 16];
        uint4 v0 = ((const uint4*)(xwd + (size_t)s0 * 16))[q];
        uint4 v1 = ((const uint4*)(xwd + (size_t)s1 * 16))[q];
        acc[0] += bflo(v0.x) + bflo(v1.x); acc[1] += bfhi(v0.x) + bfhi(v1.x);
        acc[2] += bflo(v0.y) + bflo(v1.y); acc[3] += bfhi(v0.y) + bfhi(v1.y);
        acc[4] += bflo(v0.z) + bflo(v1.z); acc[5] += bfhi(v0.z) + bfhi(v1.z);
        acc[6] += bflo(v0.w) + bflo(v1.w); acc[7] += bfhi(v0.w) + bfhi(v1.w);
    }
    for (; i < deg; i += 16) {
        int s = csr_src[off + i];
        uint4 v = ((const uint4*)(xwd + (size_t)s * 16))[q];
        acc[0] += bflo(v.x); acc[1] += bfhi(v.x);
        acc[2] += bflo(v.y); acc[3] += bfhi(v.y);
        acc[4] += bflo(v.z); acc[5] += bfhi(v.z);
        acc[6] += bflo(v.w); acc[7] += bfhi(v.w);
    }
#pragma unroll
    for (int d = 32; d >= 4; d >>= 1) {
#pragma unroll
        for (int k = 0; k < 8; ++k) acc[k] += __shfl_down(acc[k], d, 64);
    }
    if (g == 0) {
        float dv = dinv[node];
        float* op = agg + (size_t)node * 32 + q * 8;
        ((float4*)op)[0] = make_float4(acc[0] * dv, acc[1] * dv, acc[2] * dv, acc[3] * dv);
        ((float4*)op)[1] = make_float4(acc[4] * dv, acc[5] * dv, acc[6] * dv, acc[7] * dv);
    }
}

// h2wd(bf16) = (relu(agg1 + b1) @ W2) * dinv[node]
__global__ void gemm2_kernel(const float* __restrict__ agg1, const float* __restrict__ W2,
                             const float* __restrict__ b1, const float* __restrict__ dinv,
                             unsigned* __restrict__ h2wd, int N) {
    __shared__ float ws_[32 * 16];
    __shared__ float bs_[32];
    for (int i = threadIdx.x; i < 32 * 16; i += blockDim.x) ws_[i] = W2[i];
    if (threadIdx.x < 32) bs_[threadIdx.x] = b1[threadIdx.x];
    __syncthreads();
    int node = blockIdx.x * blockDim.x + threadIdx.x;
    if (node >= N) return;
    float h[32];
    const float4* ar = (const float4*)(agg1 + (size_t)node * 32);
#pragma unroll
    for (int k4 = 0; k4 < 8; ++k4) {
        float4 v = ar[k4];
        h[k4 * 4 + 0] = fmaxf(v.x + bs_[k4 * 4 + 0], 0.0f);
        h[k4 * 4 + 1] = fmaxf(v.y + bs_[k4 * 4 + 1], 0.0f);
        h[k4 * 4 + 2] = fmaxf(v.z + bs_[k4 * 4 + 2], 0.0f);
        h[k4 * 4 + 3] = fmaxf(v.w + bs_[k4 * 4 + 3], 0.0f);
    }
    float acc[16];
#pragma unroll
    for (int j = 0; j < 16; ++j) acc[j] = 0.0f;
#pragma unroll
    for (int k = 0; k < 32; ++k) {
        float hv = h[k];
#pragma unroll
        for (int j4 = 0; j4 < 4; ++j4) {
            float4 w = *(const float4*)(ws_ + k * 16 + j4 * 4);
            acc[j4 * 4 + 0] += hv * w.x;
            acc[j4 * 4 + 1] += hv * w.y;
            acc[j4 * 4 + 2] += hv * w.z;
            acc[j4 * 4 + 3] += hv * w.w;
        }
    }
    float d = dinv[node];
    unsigned pk[8];
#pragma unroll
    for (int j = 0; j < 8; ++j)
        pk[j] = f2bf(acc[2 * j] * d) | (f2bf(acc[2 * j + 1] * d) << 16);
    uint4* hp = (uint4*)(h2wd + (size_t)node * 8);
    hp[0] = make_uint4(pk[0], pk[1], pk[2], pk[3]);
    hp[1] = make_uint4(pk[4], pk[5], pk[6], pk[7]);
}

// One wave per node, bf16 rows (32B): q=lane&1, g=lane>>1 (32 groups)
// -> 32 gathers in flight. fp32 accum, agg2 written fp32.
__global__ void agg16h_kernel(const int* __restrict__ offs, const int* __restrict__ counts,
                              const int* __restrict__ csr_src, const float* __restrict__ dinv,
                              const unsigned* __restrict__ h2wd, float* __restrict__ agg, int N) {
    int wave = threadIdx.x >> 6;
    int lane = threadIdx.x & 63;
    int node = blockIdx.x * 4 + wave;
    if (node >= N) return;
    int q = lane & 1;
    int g = lane >> 1;
    int off = offs[node];
    int deg = counts[node];
    float acc[8];
#pragma unroll
    for (int k = 0; k < 8; ++k) acc[k] = 0.f;
    if (g == 0) {
        uint4 v = ((const uint4*)(h2wd + (size_t)node * 8))[q];
        acc[0] = bflo(v.x); acc[1] = bfhi(v.x);
        acc[2] = bflo(v.y); acc[3] = bfhi(v.y);
        acc[4] = bflo(v.z); acc[5] = bfhi(v.z);
        acc[6] = bflo(v.w); acc[7] = bfhi(v.w);
    }
    for (int i = g; i < deg; i += 32) {
        int s = csr_src[off + i];
        uint4 v = ((const uint4*)(h2wd + (size_t)s * 8))[q];
        acc[0] += bflo(v.x); acc[1] += bfhi(v.x);
        acc[2] += bflo(v.y); acc[3] += bfhi(v.y);
        acc[4] += bflo(v.z); acc[5] += bfhi(v.z);
        acc[6] += bflo(v.w); acc[7] += bfhi(v.w);
    }
#pragma unroll
    for (int d = 32; d >= 2; d >>= 1) {
#pragma unroll
        for (int k = 0; k < 8; ++k) acc[k] += __shfl_down(acc[k], d, 64);
    }
    if (g == 0) {
        float dv = dinv[node];
        float* op = agg + (size_t)node * 16 + q * 8;
        ((float4*)op)[0] = make_float4(acc[0] * dv, acc[1] * dv, acc[2] * dv, acc[3] * dv);
        ((float4*)op)[1] = make_float4(acc[4] * dv, acc[5] * dv, acc[6] * dv, acc[7] * dv);
    }
}

// out = relu(agg2 + b2) @ Wf + bf
__global__ void final_kernel(const float* __restrict__ agg2, const float* __restrict__ b2,
                             const float* __restrict__ Wf, const float* __restrict__ bf,
                             float* __restrict__ out, int N) {
    int i = blockIdx.x * blockDim.x + threadIdx.x;
    if (i >= N) return;
    const float4* ar = (const float4*)(agg2 + (size_t)i * 16);
    float acc = bf[0];
#pragma unroll
    for (int j4 = 0; j4 < 4; ++j4) {
        float4 v = ar[j4];
        acc += fmaxf(v.x + b2[j4 * 4 + 0], 0.0f) * Wf[j4 * 4 + 0];
        acc += fmaxf(v.y + b2[j4 * 4 + 1], 0.0f) * Wf[j4 * 4 + 1];
        acc += fmaxf(v.z + b2[j4 * 4 + 2], 0.0f) * Wf[j4 * 4 + 2];
        acc += fmaxf(v.w + b2[j4 * 4 + 3], 0.0f) * Wf[j4 * 4 + 3];
    }
    out[i] = acc;
}

extern "C" void kernel_launch(void* const* d_in, const int* in_sizes, int n_in,
                              void* d_out, int out_size, void* d_ws, size_t ws_size,
                              hipStream_t stream) {
    const float* x  = (const float*)d_in[0];
    const int*   ei = (const int*)d_in[1];
    const float* W1 = (const float*)d_in[2];
    const float* b1 = (const float*)d_in[3];
    const float* W2 = (const float*)d_in[4];
    const float* b2 = (const float*)d_in[5];
    const float* Wf = (const float*)d_in[6];
    const float* bf = (const float*)d_in[7];

    int N = in_sizes[0] / 128;
    int E = in_sizes[1] / 2;
    const int* src = ei;       // edge_index[0]
    const int* dst = ei + E;   // edge_index[1]
    int NPB = (N + NBUCK - 1) / NBUCK;  // 391 for N=100k

    // Workspace layout
    size_t Np = ((size_t)N + 3) & ~(size_t)3;
    size_t Ep = ((size_t)E + 3) & ~(size_t)3;
    int* wsI      = (int*)d_ws;
    int* counts   = wsI;                 // N
    int* offs     = counts + Np;         // N
    int* bcur     = offs + Np;           // 256
    int* bbase    = bcur + NBUCK;        // 256
    int* csr_src  = bbase + NBUCK;       // E
    float* dinv   = (float*)(csr_src + Ep);     // N
    unsigned* xwd = (unsigned*)(dinv + Np);     // 16*N u32 (bf16 rows, 64B)
    float* agg1   = (float*)(xwd + 16 * Np);    // 32*N f32
    unsigned* h2wd= (unsigned*)(agg1 + 32 * Np);// 8*N u32 (bf16 rows, 32B)
    float* agg2   = (float*)(h2wd + 8 * Np);    // 16*N f32
    float* out    = (float*)d_out;
    // Staging (16.8 MB) aliases agg1+h2wd+agg2 (22.4 MB): written by binA2,
    // read last by buildB; agg1 first written by agg32h (later). No overlap.
    unsigned* staging = (unsigned*)agg1;

    int nbG1 = (N + 63) / 64;   // 4 threads/node
    int nbC = (E + CHUNK - 1) / CHUNK;
    int nbN = (N + TPB - 1) / TPB;
    int nbW = (N + 3) / 4;  // one wave (of 4/block) per node

    zero_bcursor_kernel<<<1, NBUCK, 0, stream>>>(bcur);
    binA2_kernel<<<nbC, 256, 0, stream>>>(src, dst, bcur, staging, E, NPB);
    bucket_scan_kernel<<<1, NBUCK, 0, stream>>>(bcur, bbase);
    buildB_kernel<<<NBUCK, 512, 0, stream>>>(bcur, bbase, staging, offs, counts,
                                             dinv, csr_src, N, NPB);
    gemm1_kernel<<<nbG1, 256, 0, stream>>>(x, W1, dinv, xwd, N);
    agg32h_kernel<<<nbW, TPB, 0, stream>>>(offs, counts, csr_src, dinv, xwd, agg1, N);
    gemm2_kernel<<<nbN, TPB, 0, stream>>>(agg1, W2, b1, dinv, h2wd, N);
    agg16h_kernel<<<nbW, TPB, 0, stream>>>(offs, counts, csr_src, dinv, h2wd, agg2, N);
    final_kernel<<<nbN, TPB, 0, stream>>>(agg2, b2, Wf, bf, out, N);
}

// Round 12
// 284.911 us; speedup vs baseline: 3.7771x; 1.0057x over previous
//
#include <hip/hip_runtime.h>

// GCN forward via two-level CSR build + gather aggregation (no atomics in the
// float path — R4/R9: atomic aggregation loses 5-10x to register gather).
//   binA2: per-block LDS radix partition -> 256 dst-range buckets.
//   buildB: per-bucket LDS histogram+scan -> counts/offs/dinv + CSR.
//   gemm1: xwd = (x@W1)*dinv, BF16 rows (64B). 4 thr/node x 8 cols.
//   aggS32: lane-slice geometry — 4 lanes own one node's row (16B slices),
//     serial over edges, fp32 accum in regs, ZERO reduction shuffles
//     (R11: the 40-shuffle/node tree was ~37us of DS-pipe time).
//   gemm2: h2wd = (relu(agg1+b1)@W2)*dinv, BF16 (32B).
//   aggS16f: 2 lanes/node, serial edges, fused head (8 FMA + 1 shfl_xor)
//     writes out directly — no agg2 buffer, no final kernel.
// R7 lesson: no wave-serial (multi-step broadcast) epilogues; 1 shuffle is fine.

#define TPB 256
#define NBUCK 256
#define BCAP 16384   // bucket capacity; mean ~12512 -> large margin
#define CHUNK 8192   // edges per binA2 block

__device__ __forceinline__ unsigned f2bf(float f) {  // RNE fp32->bf16
    unsigned u = __float_as_uint(f);
    return (u + 0x7FFFu + ((u >> 16) & 1u)) >> 16;
}
__device__ __forceinline__ float bflo(unsigned u) { return __uint_as_float(u << 16); }
__device__ __forceinline__ float bfhi(unsigned u) { return __uint_as_float(u & 0xFFFF0000u); }

__global__ void zero_bcursor_kernel(int* __restrict__ bcur) {
    bcur[threadIdx.x] = 0;
}

// Phase A: block-local radix partition, then bulk append to global staging.
__global__ __launch_bounds__(256) void binA2_kernel(
        const int* __restrict__ src, const int* __restrict__ dst,
        int* __restrict__ bcur, unsigned* __restrict__ staging, int E, int NPB) {
    __shared__ unsigned packed[CHUNK];
    __shared__ unsigned char buckb[CHUNK];
    __shared__ int hist[NBUCK];
    __shared__ int scan_[NBUCK];
    __shared__ int lstart[NBUCK];
    __shared__ int lcur[NBUCK];
    __shared__ int gbase[NBUCK];
    int tid = threadIdx.x;
    int start = blockIdx.x * CHUNK;
    int sz = min(CHUNK, E - start);

    hist[tid] = 0;
    __syncthreads();
    for (int i = tid; i < sz; i += 256) {
        unsigned d = (unsigned)dst[start + i];
        atomicAdd(&hist[d / (unsigned)NPB], 1);
    }
    __syncthreads();
    int v = hist[tid];
    scan_[tid] = v;
    __syncthreads();
    for (int dd = 1; dd < NBUCK; dd <<= 1) {
        int t = 0;
        if (tid >= dd) t = scan_[tid - dd];
        __syncthreads();
        scan_[tid] += t;
        __syncthreads();
    }
    lstart[tid] = scan_[tid] - v;
    lcur[tid] = 0;
    gbase[tid] = atomicAdd(&bcur[tid], v);  // reserve once per (block,bucket)
    __syncthreads();
    for (int i = tid; i < sz; i += 256) {
        unsigned d = (unsigned)dst[start + i];
        unsigned s = (unsigned)src[start + i];
        unsigned b = d / (unsigned)NPB;
        unsigned loc = d - b * (unsigned)NPB;
        int pos = atomicAdd(&lcur[b], 1);
        int si = lstart[b] + pos;
        packed[si] = (loc << 20) | s;
        buckb[si] = (unsigned char)b;
    }
    __syncthreads();
    for (int i = tid; i < sz; i += 256) {
        unsigned b = buckb[i];
        int dsti = gbase[b] + (i - lstart[b]);
        if (dsti < BCAP)
            staging[(size_t)b * BCAP + dsti] = packed[i];
    }
}

// Exclusive scan of clamped bucket sizes -> bbase (single block of 256)
__global__ void bucket_scan_kernel(const int* __restrict__ bcur, int* __restrict__ bbase) {
    __shared__ int s[NBUCK];
    int tid = threadIdx.x;
    int v = min(bcur[tid], BCAP);
    s[tid] = v;
    __syncthreads();
    for (int d = 1; d < NBUCK; d <<= 1) {
        int t = 0;
        if (tid >= d) t = s[tid - d];
        __syncthreads();
        s[tid] += t;
        __syncthreads();
    }
    bbase[tid] = s[tid] - v;  // exclusive
}

// Phase B: one block (512 thr) per bucket. Histogram + scan + CSR placement.
__global__ void buildB_kernel(const int* __restrict__ bcur, const int* __restrict__ bbase,
                              const unsigned* __restrict__ staging,
                              int* __restrict__ offs, int* __restrict__ counts,
                              float* __restrict__ dinv, int* __restrict__ csr_src,
                              int N, int NPB) {
    __shared__ int hist[512];
    __shared__ int scan_[512];
    __shared__ int cur[512];
    int b = blockIdx.x;
    int tid = threadIdx.x;
    int sz = min(bcur[b], BCAP);
    int base = bbase[b];
    int n0 = b * NPB;
    int nn = min(NPB, N - n0);
    const unsigned* se = staging + (size_t)b * BCAP;

    hist[tid] = 0;
    __syncthreads();
    for (int i = tid; i < sz; i += 512)
        atomicAdd(&hist[se[i] >> 20], 1);
    __syncthreads();
    int h = hist[tid];
    scan_[tid] = h;
    __syncthreads();
    for (int d = 1; d < 512; d <<= 1) {
        int t = 0;
        if (tid >= d) t = scan_[tid - d];
        __syncthreads();
        scan_[tid] += t;
        __syncthreads();
    }
    int excl = scan_[tid] - h;
    cur[tid] = excl;
    if (tid < nn) {
        int node = n0 + tid;
        offs[node] = base + excl;
        counts[node] = h;
        dinv[node] = rsqrtf((float)(h + 1));  // +1 self-loop
    }
    __syncthreads();
    for (int i = tid; i < sz; i += 512) {
        unsigned p = se[i];
        int pos = atomicAdd(&cur[p >> 20], 1);
        csr_src[base + pos] = (int)(p & 0xFFFFFu);
    }
}

// xwd(bf16) = (x @ W1) * dinv[node].  4 threads/node x 8 cols; grid (N+63)/64.
__global__ __launch_bounds__(256) void gemm1_kernel(
        const float* __restrict__ x, const float* __restrict__ W1,
        const float* __restrict__ dinv, unsigned* __restrict__ xwd, int N) {
    __shared__ float ws_[128 * 32];
    for (int i = threadIdx.x; i < 128 * 32; i += blockDim.x) ws_[i] = W1[i];
    __syncthreads();
    int t = threadIdx.x;
    int node = blockIdx.x * 64 + (t >> 2);
    if (node >= N) return;
    int jq = (t & 3) * 8;  // 8 output cols
    float acc[8];
#pragma unroll
    for (int j = 0; j < 8; ++j) acc[j] = 0.0f;
    const float4* xr = (const float4*)(x + (size_t)node * 128);
#pragma unroll 4
    for (int k4 = 0; k4 < 32; ++k4) {
        float4 xv = xr[k4];
        const float* wb = ws_ + (k4 * 4) * 32 + jq;
        float4 a0 = *(const float4*)(wb);
        float4 a1 = *(const float4*)(wb + 4);
        float4 b0 = *(const float4*)(wb + 32);
        float4 b1v = *(const float4*)(wb + 36);
        float4 c0 = *(const float4*)(wb + 64);
        float4 c1 = *(const float4*)(wb + 68);
        float4 d0 = *(const float4*)(wb + 96);
        float4 d1 = *(const float4*)(wb + 100);
        acc[0] += xv.x * a0.x + xv.y * b0.x + xv.z * c0.x + xv.w * d0.x;
        acc[1] += xv.x * a0.y + xv.y * b0.y + xv.z * c0.y + xv.w * d0.y;
        acc[2] += xv.x * a0.z + xv.y * b0.z + xv.z * c0.z + xv.w * d0.z;
        acc[3] += xv.x * a0.w + xv.y * b0.w + xv.z * c0.w + xv.w * d0.w;
        acc[4] += xv.x * a1.x + xv.y * b1v.x + xv.z * c1.x + xv.w * d1.x;
        acc[5] += xv.x * a1.y + xv.y * b1v.y + xv.z * c1.y + xv.w * d1.y;
        acc[6] += xv.x * a1.z + xv.y * b1v.z + xv.z * c1.z + xv.w * d1.z;
        acc[7] += xv.x * a1.w + xv.y * b1v.w + xv.z * c1.w + xv.w * d1.w;
    }
    float d = dinv[node];
    unsigned pk0 = f2bf(acc[0] * d) | (f2bf(acc[1] * d) << 16);
    unsigned pk1 = f2bf(acc[2] * d) | (f2bf(acc[3] * d) << 16);
    unsigned pk2 = f2bf(acc[4] * d) | (f2bf(acc[5] * d) << 16);
    unsigned pk3 = f2bf(acc[6] * d) | (f2bf(acc[7] * d) << 16);
    ((uint4*)(xwd + (size_t)node * 16))[t & 3] = make_uint4(pk0, pk1, pk2, pk3);
}

// Layer-1 aggregate, lane-slice geometry: 4 lanes own node's 64B row in 16B
// slices; serial over edges (x2 unroll); fp32 accum; NO reduction shuffles.
// agg1[d] = dinv[d] * (self + sum). 64 nodes/block.
__global__ __launch_bounds__(256) void aggS32_kernel(
        const int* __restrict__ offs, const int* __restrict__ counts,
        const int* __restrict__ csr_src, const float* __restrict__ dinv,
        const unsigned* __restrict__ xwd, float* __restrict__ agg, int N) {
    int t = threadIdx.x;
    int q = t & 3;                       // 16B slice
    int node = blockIdx.x * 64 + (t >> 2);
    if (node >= N) return;
    int off = offs[node];
    int deg = counts[node];
    float acc[8];
    {
        uint4 v = ((const uint4*)(xwd + (size_t)node * 16))[q];  // self term
        acc[0] = bflo(v.x); acc[1] = bfhi(v.x);
        acc[2] = bflo(v.y); acc[3] = bfhi(v.y);
        acc[4] = bflo(v.z); acc[5] = bfhi(v.z);
        acc[6] = bflo(v.w); acc[7] = bfhi(v.w);
    }
    int i = 0;
    for (; i + 1 < deg; i += 2) {
        int s0 = csr_src[off + i];
        int s1 = csr_src[off + i + 1];
        uint4 v0 = ((const uint4*)(xwd + (size_t)s0 * 16))[q];
        uint4 v1 = ((const uint4*)(xwd + (size_t)s1 * 16))[q];
        acc[0] += bflo(v0.x) + bflo(v1.x); acc[1] += bfhi(v0.x) + bfhi(v1.x);
        acc[2] += bflo(v0.y) + bflo(v1.y); acc[3] += bfhi(v0.y) + bfhi(v1.y);
        acc[4] += bflo(v0.z) + bflo(v1.z); acc[5] += bfhi(v0.z) + bfhi(v1.z);
        acc[6] += bflo(v0.w) + bflo(v1.w); acc[7] += bfhi(v0.w) + bfhi(v1.w);
    }
    if (i < deg) {
        int s = csr_src[off + i];
        uint4 v = ((const uint4*)(xwd + (size_t)s * 16))[q];
        acc[0] += bflo(v.x); acc[1] += bfhi(v.x);
        acc[2] += bflo(v.y); acc[3] += bfhi(v.y);
        acc[4] += bflo(v.z); acc[5] += bfhi(v.z);
        acc[6] += bflo(v.w); acc[7] += bfhi(v.w);
    }
    float dv = dinv[node];
    float* op = agg + (size_t)node * 32 + q * 8;
    ((float4*)op)[0] = make_float4(acc[0] * dv, acc[1] * dv, acc[2] * dv, acc[3] * dv);
    ((float4*)op)[1] = make_float4(acc[4] * dv, acc[5] * dv, acc[6] * dv, acc[7] * dv);
}

// h2wd(bf16) = (relu(agg1 + b1) @ W2) * dinv[node]
__global__ void gemm2_kernel(const float* __restrict__ agg1, const float* __restrict__ W2,
                             const float* __restrict__ b1, const float* __restrict__ dinv,
                             unsigned* __restrict__ h2wd, int N) {
    __shared__ float ws_[32 * 16];
    __shared__ float bs_[32];
    for (int i = threadIdx.x; i < 32 * 16; i += blockDim.x) ws_[i] = W2[i];
    if (threadIdx.x < 32) bs_[threadIdx.x] = b1[threadIdx.x];
    __syncthreads();
    int node = blockIdx.x * blockDim.x + threadIdx.x;
    if (node >= N) return;
    float h[32];
    const float4* ar = (const float4*)(agg1 + (size_t)node * 32);
#pragma unroll
    for (int k4 = 0; k4 < 8; ++k4) {
        float4 v = ar[k4];
        h[k4 * 4 + 0] = fmaxf(v.x + bs_[k4 * 4 + 0], 0.0f);
        h[k4 * 4 + 1] = fmaxf(v.y + bs_[k4 * 4 + 1], 0.0f);
        h[k4 * 4 + 2] = fmaxf(v.z + bs_[k4 * 4 + 2], 0.0f);
        h[k4 * 4 + 3] = fmaxf(v.w + bs_[k4 * 4 + 3], 0.0f);
    }
    float acc[16];
#pragma unroll
    for (int j = 0; j < 16; ++j) acc[j] = 0.0f;
#pragma unroll
    for (int k = 0; k < 32; ++k) {
        float hv = h[k];
#pragma unroll
        for (int j4 = 0; j4 < 4; ++j4) {
            float4 w = *(const float4*)(ws_ + k * 16 + j4 * 4);
            acc[j4 * 4 + 0] += hv * w.x;
            acc[j4 * 4 + 1] += hv * w.y;
            acc[j4 * 4 + 2] += hv * w.z;
            acc[j4 * 4 + 3] += hv * w.w;
        }
    }
    float d = dinv[node];
    unsigned pk[8];
#pragma unroll
    for (int j = 0; j < 8; ++j)
        pk[j] = f2bf(acc[2 * j] * d) | (f2bf(acc[2 * j + 1] * d) << 16);
    uint4* hp = (uint4*)(h2wd + (size_t)node * 8);
    hp[0] = make_uint4(pk[0], pk[1], pk[2], pk[3]);
    hp[1] = make_uint4(pk[4], pk[5], pk[6], pk[7]);
}

// Layer-2 aggregate + fused head, lane-slice: 2 lanes own node's 32B row;
// serial edges (x2 unroll); epilogue = 8 FMA dot + ONE shfl_xor -> out.
// 128 nodes/block.
__global__ __launch_bounds__(256) void aggS16f_kernel(
        const int* __restrict__ offs, const int* __restrict__ counts,
        const int* __restrict__ csr_src, const float* __restrict__ dinv,
        const unsigned* __restrict__ h2wd,
        const float* __restrict__ b2, const float* __restrict__ Wf,
        const float* __restrict__ bf, float* __restrict__ out, int N) {
    __shared__ float bs_[16];
    __shared__ float wf_[16];
    __shared__ float bfv;
    int t = threadIdx.x;
    if (t < 16) { bs_[t] = b2[t]; wf_[t] = Wf[t]; }
    if (t == 0) bfv = bf[0];
    __syncthreads();
    int q = t & 1;                        // 16B slice (8 feats)
    int node = blockIdx.x * 128 + (t >> 1);
    if (node >= N) return;
    int off = offs[node];
    int deg = counts[node];
    float acc[8];
    {
        uint4 v = ((const uint4*)(h2wd + (size_t)node * 8))[q];  // self term
        acc[0] = bflo(v.x); acc[1] = bfhi(v.x);
        acc[2] = bflo(v.y); acc[3] = bfhi(v.y);
        acc[4] = bflo(v.z); acc[5] = bfhi(v.z);
        acc[6] = bflo(v.w); acc[7] = bfhi(v.w);
    }
    int i = 0;
    for (; i + 1 < deg; i += 2) {
        int s0 = csr_src[off + i];
        int s1 = csr_src[off + i + 1];
        uint4 v0 = ((const uint4*)(h2wd + (size_t)s0 * 8))[q];
        uint4 v1 = ((const uint4*)(h2wd + (size_t)s1 * 8))[q];
        acc[0] += bflo(v0.x) + bflo(v1.x); acc[1] += bfhi(v0.x) + bfhi(v1.x);
        acc[2] += bflo(v0.y) + bflo(v1.y); acc[3] += bfhi(v0.y) + bfhi(v1.y);
        acc[4] += bflo(v0.z) + bflo(v1.z); acc[5] += bfhi(v0.z) + bfhi(v1.z);
        acc[6] += bflo(v0.w) + bflo(v1.w); acc[7] += bfhi(v0.w) + bfhi(v1.w);
    }
    if (i < deg) {
        int s = csr_src[off + i];
        uint4 v = ((const uint4*)(h2wd + (size_t)s * 8))[q];
        acc[0] += bflo(v.x); acc[1] += bfhi(v.x);
        acc[2] += bflo(v.y); acc[3] += bfhi(v.y);
        acc[4] += bflo(v.z); acc[5] += bfhi(v.z);
        acc[6] += bflo(v.w); acc[7] += bfhi(v.w);
    }
    // fused head: out[node] = relu(acc*dv + b2) . Wf + bf  (pair-split dot)
    float dv = dinv[node];
    const float* bq = bs_ + q * 8;
    const float* wq = wf_ + q * 8;
    float part = 0.f;
#pragma unroll
    for (int k = 0; k < 8; ++k)
        part += fmaxf(acc[k] * dv + bq[k], 0.f) * wq[k];
    part += __shfl_xor(part, 1, 64);  // combine the pair's halves
    if (q == 0) out[node] = part + bfv;
}

extern "C" void kernel_launch(void* const* d_in, const int* in_sizes, int n_in,
                              void* d_out, int out_size, void* d_ws, size_t ws_size,
                              hipStream_t stream) {
    const float* x  = (const float*)d_in[0];
    const int*   ei = (const int*)d_in[1];
    const float* W1 = (const float*)d_in[2];
    const float* b1 = (const float*)d_in[3];
    const float* W2 = (const float*)d_in[4];
    const float* b2 = (const float*)d_in[5];
    const float* Wf = (const float*)d_in[6];
    const float* bf = (const float*)d_in[7];

    int N = in_sizes[0] / 128;
    int E = in_sizes[1] / 2;
    const int* src = ei;       // edge_index[0]
    const int* dst = ei + E;   // edge_index[1]
    int NPB = (N + NBUCK - 1) / NBUCK;  // 391 for N=100k

    // Workspace layout (agg2 slot retained as staging tail padding)
    size_t Np = ((size_t)N + 3) & ~(size_t)3;
    size_t Ep = ((size_t)E + 3) & ~(size_t)3;
    int* wsI      = (int*)d_ws;
    int* counts   = wsI;                 // N
    int* offs     = counts + Np;         // N
    int* bcur     = offs + Np;           // 256
    int* bbase    = bcur + NBUCK;        // 256
    int* csr_src  = bbase + NBUCK;       // E
    float* dinv   = (float*)(csr_src + Ep);     // N
    unsigned* xwd = (unsigned*)(dinv + Np);     // 16*N u32 (bf16 rows, 64B)
    float* agg1   = (float*)(xwd + 16 * Np);    // 32*N f32
    unsigned* h2wd= (unsigned*)(agg1 + 32 * Np);// 8*N u32 (bf16 rows, 32B)
    float* out    = (float*)d_out;
    // Staging (16.8 MB) aliases agg1+h2wd+tail (22.4 MB): written by binA2,
    // read last by buildB; agg1 first written by aggS32 (later). No overlap.
    unsigned* staging = (unsigned*)agg1;

    int nbG1 = (N + 63) / 64;    // 4 threads/node
    int nbC  = (E + CHUNK - 1) / CHUNK;
    int nbN  = (N + TPB - 1) / TPB;
    int nbA32 = (N + 63) / 64;   // 64 nodes/block (4 lanes/node)
    int nbA16 = (N + 127) / 128; // 128 nodes/block (2 lanes/node)

    zero_bcursor_kernel<<<1, NBUCK, 0, stream>>>(bcur);
    binA2_kernel<<<nbC, 256, 0, stream>>>(src, dst, bcur, staging, E, NPB);
    bucket_scan_kernel<<<1, NBUCK, 0, stream>>>(bcur, bbase);
    buildB_kernel<<<NBUCK, 512, 0, stream>>>(bcur, bbase, staging, offs, counts,
                                             dinv, csr_src, N, NPB);
    gemm1_kernel<<<nbG1, 256, 0, stream>>>(x, W1, dinv, xwd, N);
    aggS32_kernel<<<nbA32, 256, 0, stream>>>(offs, counts, csr_src, dinv, xwd, agg1, N);
    gemm2_kernel<<<nbN, TPB, 0, stream>>>(agg1, W2, b1, dinv, h2wd, N);
    aggS16f_kernel<<<nbA16, 256, 0, stream>>>(offs, counts, csr_src, dinv, h2wd,
                                              b2, Wf, bf, out, N);
}